// Round 4
// baseline (36.413 us; speedup 1.0000x reference)
//
#include <hip/hip_runtime.h>
#include <math.h>

#define EPS 1e-12f

constexpr int N = 1024;
constexpr int F = 256;
constexpr unsigned NBLK  = 256;   // producer blocks (4 n each)
constexpr unsigned NCONS = 64;    // consumer blocks (1 pair each)
constexpr size_t COUNTER_OFF = (size_t)64 * 1024 * sizeof(float);  // after v

union SharedU {
    float4 rows[4][16][64];                           // phase 1: [sub][row][lane], 64 KB
    struct { float s[N]; float rbuf[16][6]; } p2;     // phase 2: 4.4 KB
};

template <int CTRL>
__device__ __forceinline__ float dppAdd(float x) {
    int y = __builtin_amdgcn_update_dpp(0, __float_as_int(x), CTRL, 0xf, 0xf, true);
    return x + __int_as_float(y);
}
// Full wave-64 sum, VALU-only (no DS pipe). Valid in lane 63.
__device__ __forceinline__ float waveSum64(float x) {
    x = dppAdd<0x111>(x);   // row_shr:1
    x = dppAdd<0x112>(x);   // row_shr:2
    x = dppAdd<0x114>(x);   // row_shr:4
    x = dppAdd<0x118>(x);   // row_shr:8  -> lane15 of each row = row sum
    x = dppAdd<0x142>(x);   // row_bcast:15
    x = dppAdd<0x143>(x);   // row_bcast:31 -> lane63 = total
    return x;
}

__device__ __forceinline__ float dot4(float4 a, float4 b) {
    return a.x * b.x + a.y * b.y + a.z * b.z + a.w * b.w;
}

__device__ inline void atomicMaxFloat(float* addr, float val) {
    unsigned int* ua = (unsigned int*)addr;
    unsigned int old = __hip_atomic_load(ua, __ATOMIC_RELAXED, __HIP_MEMORY_SCOPE_AGENT);
    while (__uint_as_float(old) < val) {
        unsigned int assumed = old;
        old = atomicCAS(ua, assumed, __float_as_uint(val));
        if (old == assumed) break;
    }
}

__global__ __launch_bounds__(1024) void fused_kernel(const float* __restrict__ gfa,
                                                     const float* __restrict__ ca,
                                                     const float* __restrict__ gfb,
                                                     const float* __restrict__ cb,
                                                     float* __restrict__ v,
                                                     unsigned* __restrict__ counter,
                                                     float* __restrict__ out) {
    __shared__ SharedU sh;
    const unsigned b    = blockIdx.x;      // 0..255
    const unsigned tid  = threadIdx.x;     // 0..1023
    const unsigned sub  = tid >> 8;        // 0..3
    const unsigned t    = tid & 255;       // 0..255 within sub
    const unsigned lane = tid & 63;
    const unsigned wv   = t >> 6;          // wave within sub: 0..3
    const unsigned n    = b * 4 + sub;     // 0..1023

    if (b == 0 && tid == 0)
        __hip_atomic_store(out, -INFINITY, __ATOMIC_RELAXED, __HIP_MEMORY_SCOPE_AGENT);

    // ---------------- phase 1: normalized dots v[p][n] ----------------
    #pragma unroll
    for (int rep = 0; rep < 4; ++rep) {
        const int idx = rep * 256 + (int)t;   // 0..1023
        const int row = idx >> 6;             // 0..15
        const int c4  = idx & 63;
        const float* src = (row < 8) ? gfa + ((size_t)row * N + n) * F
                                     : gfb + ((size_t)(row - 8) * N + n) * F;
        sh.rows[sub][row][c4] = ((const float4*)src)[c4];
    }
    __syncthreads();

    {
        const int ra0 = 2 * (int)wv, ra1 = ra0 + 1;
        const float4 a0 = sh.rows[sub][ra0][lane];
        const float4 a1 = sh.rows[sub][ra1][lane];
        float4 bb[8];
        #pragma unroll
        for (int rb = 0; rb < 8; ++rb) bb[rb] = sh.rows[sub][8 + rb][lane];

        // 26 independent DPP reductions (good ILP), results land in lane 63.
        float na0 = waveSum64(dot4(a0, a0));
        float na1 = waveSum64(dot4(a1, a1));
        float nb[8], d0[8], d1[8];
        #pragma unroll
        for (int rb = 0; rb < 8; ++rb) {
            nb[rb] = waveSum64(dot4(bb[rb], bb[rb]));
            d0[rb] = waveSum64(dot4(a0, bb[rb]));
            d1[rb] = waveSum64(dot4(a1, bb[rb]));
        }
        if (lane == 63) {
            const float ia0 = 1.f / fmaxf(sqrtf(na0), EPS);
            const float ia1 = 1.f / fmaxf(sqrtf(na1), EPS);
            #pragma unroll
            for (int rb = 0; rb < 8; ++rb) {
                const float ib = 1.f / fmaxf(sqrtf(nb[rb]), EPS);
                v[(size_t)(ra0 * 8 + rb) * N + n] = d0[rb] * ia0 * ib;
                v[(size_t)(ra1 * 8 + rb) * N + n] = d1[rb] * ia1 * ib;
            }
        }
    }

    // ---------------- grid barrier (device-scope) ----------------
    __syncthreads();    // all waves' v-stores issued & drained before the count
    if (tid == 0)
        __hip_atomic_fetch_add(counter, 1u, __ATOMIC_RELEASE, __HIP_MEMORY_SCOPE_AGENT);

    if (b >= NCONS) return;   // pure producers exit, freeing CUs

    if (tid == 0) {
        while (__hip_atomic_load(counter, __ATOMIC_RELAXED, __HIP_MEMORY_SCOPE_AGENT) < NBLK)
            __builtin_amdgcn_s_sleep(2);
        __threadfence();   // device-scope acquire: v[] visible after counter==NBLK
    }
    __syncthreads();

    // ---------------- phase 2: pair p = b ----------------
    const int p = (int)b;
    const int ra = p >> 3, rb = p & 7;
    const int i = (int)tid;

    float x = v[(size_t)p * N + i];

    // Hybrid bitonic sort ascending: j<64 via shuffles, j>=64 via LDS.
    #pragma unroll
    for (int k = 2; k <= 64; k <<= 1) {
        #pragma unroll
        for (int j = k >> 1; j >= 1; j >>= 1) {
            const float y = __shfl_xor(x, j);
            const bool keepMin = (((i & j) == 0) == ((i & k) == 0));
            x = keepMin ? fminf(x, y) : fmaxf(x, y);
        }
    }
    #pragma unroll
    for (int k = 128; k <= 1024; k <<= 1) {
        for (int j = k >> 1; j >= 64; j >>= 1) {
            sh.p2.s[i] = x;
            __syncthreads();
            const float y = sh.p2.s[i ^ j];
            const bool keepMin = (((i & j) == 0) == ((i & k) == 0));
            x = keepMin ? fminf(x, y) : fmaxf(x, y);
            __syncthreads();
        }
        #pragma unroll
        for (int j = 32; j >= 1; j >>= 1) {
            const float y = __shfl_xor(x, j);
            const bool keepMin = (((i & j) == 0) == ((i & k) == 0));
            x = keepMin ? fminf(x, y) : fmaxf(x, y);
        }
    }
    sh.p2.s[i] = x;           // sorted ascending
    __syncthreads();

    const float vmin = sh.p2.s[0];
    const float u = sh.p2.s[N - 1 - i] - vmin;     // weight at descending rank i
    const float t16 = (i >= N - 16) ? x : 0.f;     // top-16 values

    const float2 cA = ((const float2*)ca)[(size_t)ra * N + i];
    const float2 cB = ((const float2*)cb)[(size_t)rb * N + i];
    const float ex = cA.x - cB.x;
    const float ey = cA.y - cB.y;
    const float e2 = ex * ex + ey * ey;

    float vals[6] = { u, u * u, u * e2, u * ex, u * ey, t16 };

    const int wave = i >> 6;
    #pragma unroll
    for (int m = 0; m < 6; ++m) {
        float r = vals[m];
        #pragma unroll
        for (int off = 32; off; off >>= 1) r += __shfl_down(r, off);
        if (lane == 0) sh.p2.rbuf[wave][m] = r;
    }
    __syncthreads();

    if (wave == 0) {
        float acc[6];
        #pragma unroll
        for (int m = 0; m < 6; ++m) {
            float r = (lane < 16) ? sh.p2.rbuf[lane][m] : 0.f;
            r += __shfl_down(r, 8);
            r += __shfl_down(r, 4);
            r += __shfl_down(r, 2);
            r += __shfl_down(r, 1);
            acc[m] = r;
        }
        if (lane == 0) {
            const float Su = acc[0], U2 = acc[1], A = acc[2];
            const float Bx = acc[3], By = acc[4], T = acc[5];
            const float sim_feat = T * (1.f / 16.f);
            const float denom = (float)N * (float)N * fmaxf(U2, EPS);
            const float dis_loc = (2.f * Su * A - 2.f * (Bx * Bx + By * By)) / denom;
            atomicMaxFloat(out, sim_feat - dis_loc);
        }
    }
}

extern "C" void kernel_launch(void* const* d_in, const int* in_sizes, int n_in,
                              void* d_out, int out_size, void* d_ws, size_t ws_size,
                              hipStream_t stream) {
    const float* gfa = (const float*)d_in[0];  // (8,1024,256)
    const float* ca  = (const float*)d_in[1];  // (8,1024,2)
    const float* gfb = (const float*)d_in[2];  // (8,1024,256)
    const float* cb  = (const float*)d_in[3];  // (8,1024,2)
    float* out = (float*)d_out;

    float*    v       = (float*)d_ws;                            // 256 KB
    unsigned* counter = (unsigned*)((char*)d_ws + COUNTER_OFF);  // 4 B

    (void)hipMemsetAsync(counter, 0, sizeof(unsigned), stream);
    fused_kernel<<<NBLK, 1024, 0, stream>>>(gfa, ca, gfb, cb, v, counter, out);
}

// Round 6
// 25.480 us; speedup vs baseline: 1.4291x; 1.4291x over previous
//
#include <hip/hip_runtime.h>
#include <math.h>

#define EPS 1e-12f

constexpr int N = 1024;
constexpr int F = 256;

template <int CTRL>
__device__ __forceinline__ float dppAdd(float x) {
    int y = __builtin_amdgcn_update_dpp(0, __float_as_int(x), CTRL, 0xf, 0xf, true);
    return x + __int_as_float(y);
}
// Full wave-64 sum, VALU-only (no DS pipe). Valid in lane 63. (HW-validated round 4.)
__device__ __forceinline__ float waveSum64(float x) {
    x = dppAdd<0x111>(x);   // row_shr:1
    x = dppAdd<0x112>(x);   // row_shr:2
    x = dppAdd<0x114>(x);   // row_shr:4
    x = dppAdd<0x118>(x);   // row_shr:8
    x = dppAdd<0x142>(x);   // row_bcast:15
    x = dppAdd<0x143>(x);   // row_bcast:31 -> lane63 = total
    return x;
}

__device__ __forceinline__ float dot4(float4 a, float4 b) {
    return a.x * b.x + a.y * b.y + a.z * b.z + a.w * b.w;
}

__device__ inline void atomicMaxFloat(float* addr, float val) {
    unsigned int* ua = (unsigned int*)addr;
    unsigned int old = __hip_atomic_load(ua, __ATOMIC_RELAXED, __HIP_MEMORY_SCOPE_AGENT);
    while (__uint_as_float(old) < val) {
        unsigned int assumed = old;
        old = atomicCAS(ua, assumed, __float_as_uint(val));
        if (old == assumed) break;
    }
}

// Kernel 1 (proven in round 4): 256 blocks x 1024 threads; each 256-thread
// sub-group handles one n: stage 16 rows in LDS, 26 DPP reductions per wave,
// lane 63 writes 16 normalized dots. Also inits out[0] = -inf.
__global__ __launch_bounds__(1024) void dot_kernel(const float* __restrict__ gfa,
                                                   const float* __restrict__ gfb,
                                                   float* __restrict__ v,
                                                   float* __restrict__ out) {
    __shared__ float4 rows[4][16][64];     // [sub][row][lane4], 64 KB
    const unsigned b    = blockIdx.x;      // 0..255
    const unsigned tid  = threadIdx.x;     // 0..1023
    const unsigned sub  = tid >> 8;        // 0..3
    const unsigned t    = tid & 255;       // 0..255
    const unsigned lane = tid & 63;
    const unsigned wv   = t >> 6;          // 0..3
    const unsigned n    = b * 4 + sub;     // 0..1023

    if (b == 0 && tid == 0)
        __hip_atomic_store(out, -INFINITY, __ATOMIC_RELAXED, __HIP_MEMORY_SCOPE_AGENT);

    #pragma unroll
    for (int rep = 0; rep < 4; ++rep) {
        const int idx = rep * 256 + (int)t;   // 0..1023
        const int row = idx >> 6;             // 0..15 (wave-uniform)
        const int c4  = idx & 63;
        const float* src = (row < 8) ? gfa + ((size_t)row * N + n) * F
                                     : gfb + ((size_t)(row - 8) * N + n) * F;
        rows[sub][row][c4] = ((const float4*)src)[c4];
    }
    __syncthreads();

    const int ra0 = 2 * (int)wv, ra1 = ra0 + 1;
    const float4 a0 = rows[sub][ra0][lane];
    const float4 a1 = rows[sub][ra1][lane];
    float4 bb[8];
    #pragma unroll
    for (int rb = 0; rb < 8; ++rb) bb[rb] = rows[sub][8 + rb][lane];

    float na0 = waveSum64(dot4(a0, a0));
    float na1 = waveSum64(dot4(a1, a1));
    float nb[8], d0[8], d1[8];
    #pragma unroll
    for (int rb = 0; rb < 8; ++rb) {
        nb[rb] = waveSum64(dot4(bb[rb], bb[rb]));
        d0[rb] = waveSum64(dot4(a0, bb[rb]));
        d1[rb] = waveSum64(dot4(a1, bb[rb]));
    }
    if (lane == 63) {
        const float ia0 = 1.f / fmaxf(sqrtf(na0), EPS);
        const float ia1 = 1.f / fmaxf(sqrtf(na1), EPS);
        #pragma unroll
        for (int rb = 0; rb < 8; ++rb) {
            const float ib = 1.f / fmaxf(sqrtf(nb[rb]), EPS);
            v[(size_t)(ra0 * 8 + rb) * N + n] = d0[rb] * ia0 * ib;
            v[(size_t)(ra1 * 8 + rb) * N + n] = d1[rb] * ia1 * ib;
        }
    }
}

// Kernel 2: ONE WAVE PER PAIR. Register bitonic sort of 1024 floats
// (16 per lane, i = lane*16 + e): j<16 phases intra-lane (pure VALU),
// j>=16 via shfl_xor. No LDS, no __syncthreads.
// Bitonic rule: in an ascending block the LOWER partner keeps the min,
// i.e. keepMin = (hiLane != up).  (Round-5 bug: this was inverted.)
__global__ __launch_bounds__(64) void pair_kernel(const float* __restrict__ v,
                                                  const float* __restrict__ ca,
                                                  const float* __restrict__ cb,
                                                  float* __restrict__ out) {
    const int p = blockIdx.x;        // 0..63
    const int ra = p >> 3, rb = p & 7;
    const int lane = threadIdx.x;    // 0..63

    // Issue coord loads first so they're in flight under the sort.
    const float4* pa4 = (const float4*)(ca + ((size_t)ra * N + lane * 16) * 2);
    const float4* pb4 = (const float4*)(cb + ((size_t)rb * N + lane * 16) * 2);
    float4 va[8], vb[8];
    #pragma unroll
    for (int q = 0; q < 8; ++q) { va[q] = pa4[q]; vb[q] = pb4[q]; }

    float x[16];
    const float4* pv = (const float4*)(v + (size_t)p * N + lane * 16);
    #pragma unroll
    for (int q = 0; q < 4; ++q) {
        const float4 t = pv[q];
        x[4*q+0] = t.x; x[4*q+1] = t.y; x[4*q+2] = t.z; x[4*q+3] = t.w;
    }

    // Bitonic sort ascending over i = lane*16 + e.
    #pragma unroll
    for (int k = 2; k <= 1024; k <<= 1) {
        #pragma unroll
        for (int j = k >> 1; j >= 1; j >>= 1) {
            if (j >= 16) {                       // cross-lane, e preserved (k >= 32)
                const int J = j >> 4;
                const bool up = ((lane & (k >> 4)) == 0);
                const bool hiLane = ((lane & J) != 0);
                const bool keepMin = (hiLane != up);
                #pragma unroll
                for (int e = 0; e < 16; ++e) {
                    const float y = __shfl_xor(x[e], J);
                    x[e] = keepMin ? fminf(x[e], y) : fmaxf(x[e], y);
                }
            } else {                             // intra-lane compare-exchange
                #pragma unroll
                for (int e = 0; e < 16; ++e) {
                    if ((e & j) == 0) {
                        const int f = e | j;
                        bool up;
                        if (k >= 32)      up = ((lane & (k >> 4)) == 0);
                        else if (k == 16) up = ((lane & 1) == 0);
                        else              up = ((e & k) == 0);
                        const float a = x[e], b2 = x[f];
                        x[e] = up ? fminf(a, b2) : fmaxf(a, b2);
                        x[f] = up ? fmaxf(a, b2) : fminf(a, b2);
                    }
                }
            }
        }
    }

    // vmin = global min (asc rank 0 = lane 0 elem 0).
    const float vmin = __shfl(x[0], 0);

    // lane 63 holds asc ranks 1008..1023 = the top-16 values.
    float t16 = 0.f;
    #pragma unroll
    for (int e = 0; e < 16; ++e) t16 += x[e];    // meaningful on lane 63

    // Descending-rank value for original index r = lane*16+e:
    // asc rank 1023-r = elem (15-e) of lane (63-lane)  -> shfl_xor(·, 63).
    float u[16];
    #pragma unroll
    for (int e = 0; e < 16; ++e) u[e] = __shfl_xor(x[15 - e], 63) - vmin;

    float Su = 0.f, U2 = 0.f, A = 0.f, Bx = 0.f, By = 0.f;
    #pragma unroll
    for (int q = 0; q < 8; ++q) {
        const float4 a4 = va[q], b4 = vb[q];
        {
            const float uu = u[2*q];
            const float ex = a4.x - b4.x, ey = a4.y - b4.y;
            Su += uu; U2 += uu * uu;
            A  += uu * (ex * ex + ey * ey);
            Bx += uu * ex; By += uu * ey;
        }
        {
            const float uu = u[2*q+1];
            const float ex = a4.z - b4.z, ey = a4.w - b4.w;
            Su += uu; U2 += uu * uu;
            A  += uu * (ex * ex + ey * ey);
            Bx += uu * ex; By += uu * ey;
        }
    }

    Su = waveSum64(Su); U2 = waveSum64(U2); A = waveSum64(A);
    Bx = waveSum64(Bx); By = waveSum64(By);

    if (lane == 63) {
        const float sim_feat = t16 * (1.f / 16.f);
        const float denom = (float)N * (float)N * fmaxf(U2, EPS);
        const float dis_loc = (2.f * Su * A - 2.f * (Bx * Bx + By * By)) / denom;
        atomicMaxFloat(out, sim_feat - dis_loc);
    }
}

extern "C" void kernel_launch(void* const* d_in, const int* in_sizes, int n_in,
                              void* d_out, int out_size, void* d_ws, size_t ws_size,
                              hipStream_t stream) {
    const float* gfa = (const float*)d_in[0];  // (8,1024,256)
    const float* ca  = (const float*)d_in[1];  // (8,1024,2)
    const float* gfb = (const float*)d_in[2];  // (8,1024,256)
    const float* cb  = (const float*)d_in[3];  // (8,1024,2)
    float* out = (float*)d_out;

    float* v = (float*)d_ws;                   // 64*1024 floats = 256 KB

    dot_kernel<<<256, 1024, 0, stream>>>(gfa, gfb, v, out);
    pair_kernel<<<64, 64, 0, stream>>>(v, ca, cb, out);
}

// Round 7
// 20.711 us; speedup vs baseline: 1.7582x; 1.2303x over previous
//
#include <hip/hip_runtime.h>
#include <math.h>

#define EPS 1e-12f

constexpr int N = 1024;
constexpr int F = 256;
constexpr int NPAIR = 64;

template <int CTRL>
__device__ __forceinline__ float dppAdd(float x) {
    int y = __builtin_amdgcn_update_dpp(0, __float_as_int(x), CTRL, 0xf, 0xf, true);
    return x + __int_as_float(y);
}
// Full wave-64 sum, VALU-only. Valid in lane 63. (HW-validated rounds 4/6.)
__device__ __forceinline__ float waveSum64(float x) {
    x = dppAdd<0x111>(x);   // row_shr:1
    x = dppAdd<0x112>(x);   // row_shr:2
    x = dppAdd<0x114>(x);   // row_shr:4
    x = dppAdd<0x118>(x);   // row_shr:8
    x = dppAdd<0x142>(x);   // row_bcast:15
    x = dppAdd<0x143>(x);   // row_bcast:31 -> lane63 = total
    return x;
}

__device__ inline void atomicMaxFloat(float* addr, float val) {
    unsigned int* ua = (unsigned int*)addr;
    unsigned int old = __hip_atomic_load(ua, __ATOMIC_RELAXED, __HIP_MEMORY_SCOPE_AGENT);
    while (__uint_as_float(old) < val) {
        unsigned int assumed = old;
        old = atomicCAS(ua, assumed, __float_as_uint(val));
        if (old == assumed) break;
    }
}

// Kernel 1: VERBATIM from round 2's 23.2 us config. One block per n.
__global__ __launch_bounds__(256) void dot_kernel(const float* __restrict__ gfa,
                                                  const float* __restrict__ gfb,
                                                  float* __restrict__ v,
                                                  float* __restrict__ out) {
    const int n = blockIdx.x;     // 0..N-1
    const int t = threadIdx.x;    // 0..255
    __shared__ float4 rows[16][64];   // rows 0..7 = A, 8..15 = B
    __shared__ float invn[16];

    if (n == 0 && t == 0) out[0] = -INFINITY;

    #pragma unroll
    for (int rep = 0; rep < 4; ++rep) {
        const int idx = rep * 256 + t;      // 0..1023
        const int row = idx >> 6;           // 0..15
        const int c4  = idx & 63;
        const float* src = (row < 8) ? gfa + ((size_t)row * N + n) * F
                                     : gfb + ((size_t)(row - 8) * N + n) * F;
        rows[row][c4] = ((const float4*)src)[c4];
    }
    __syncthreads();

    const int wave = t >> 6, lane = t & 63;

    #pragma unroll
    for (int rr = 0; rr < 4; ++rr) {
        const int row = wave * 4 + rr;
        const float4 a = rows[row][lane];
        float ss = a.x * a.x + a.y * a.y + a.z * a.z + a.w * a.w;
        #pragma unroll
        for (int off = 32; off; off >>= 1) ss += __shfl_down(ss, off);
        if (lane == 0) invn[row] = 1.f / fmaxf(sqrtf(ss), EPS);
    }
    __syncthreads();

    float4 b[8];
    #pragma unroll
    for (int rb = 0; rb < 8; ++rb) b[rb] = rows[8 + rb][lane];

    #pragma unroll
    for (int rr = 0; rr < 2; ++rr) {
        const int ra = wave * 2 + rr;
        const float4 a = rows[ra][lane];
        #pragma unroll
        for (int rb = 0; rb < 8; ++rb) {
            float d = a.x * b[rb].x + a.y * b[rb].y + a.z * b[rb].z + a.w * b[rb].w;
            #pragma unroll
            for (int off = 32; off; off >>= 1) d += __shfl_down(d, off);
            if (lane == 0)
                v[(size_t)(ra * 8 + rb) * N + n] = d * invn[ra] * invn[8 + rb];
        }
    }
}

// Kernel 2: 64 blocks x 256 threads (4 waves). Register bitonic sort,
// 4 elements per lane, i = tid*4 + e. j<4 intra-lane, 4<=j<=128 shfl_xor,
// j>=256 via LDS (only 3 phases -> 6 barriers total).
__global__ __launch_bounds__(256) void pair_kernel(const float* __restrict__ v,
                                                   const float* __restrict__ ca,
                                                   const float* __restrict__ cb,
                                                   float* __restrict__ out) {
    const int p = blockIdx.x;        // 0..63
    const int ra = p >> 3, rb = p & 7;
    const int tid = threadIdx.x;     // 0..255
    const int lane = tid & 63, wv = tid >> 6;
    __shared__ float s[N];
    __shared__ float rbuf[4][6];

    // Coord loads issued early (original indices r = 4*tid .. 4*tid+3).
    const float4* pa4 = (const float4*)(ca + (size_t)ra * N * 2) + tid * 2;
    const float4* pb4 = (const float4*)(cb + (size_t)rb * N * 2) + tid * 2;
    const float4 a01 = pa4[0], a23 = pa4[1];
    const float4 b01 = pb4[0], b23 = pb4[1];

    const float4 xv = ((const float4*)(v + (size_t)p * N))[tid];
    float x[4] = { xv.x, xv.y, xv.z, xv.w };

    // Bitonic sort ascending over i = tid*4 + e.
    // keepMin = (hiPartner != ascending)  [R2-proven predicate]
    #pragma unroll
    for (int k = 2; k <= 1024; k <<= 1) {
        #pragma unroll
        for (int j = k >> 1; j >= 1; j >>= 1) {
            if (j >= 256) {                      // cross-wave via LDS
                ((float4*)s)[tid] = make_float4(x[0], x[1], x[2], x[3]);
                __syncthreads();
                const float4 yv = ((const float4*)s)[tid ^ (j >> 2)];
                const float y[4] = { yv.x, yv.y, yv.z, yv.w };
                const bool up = ((tid & (k >> 2)) == 0);
                const bool hi = ((tid & (j >> 2)) != 0);
                const bool keepMin = (hi != up);
                #pragma unroll
                for (int e = 0; e < 4; ++e)
                    x[e] = keepMin ? fminf(x[e], y[e]) : fmaxf(x[e], y[e]);
                __syncthreads();
            } else if (j >= 4) {                 // cross-lane within wave
                const int J = j >> 2;            // 1..32
                const bool up = ((tid & (k >> 2)) == 0);   // k >= 8 here
                const bool hi = ((lane & J) != 0);
                const bool keepMin = (hi != up);
                #pragma unroll
                for (int e = 0; e < 4; ++e) {
                    const float y = __shfl_xor(x[e], J);
                    x[e] = keepMin ? fminf(x[e], y) : fmaxf(x[e], y);
                }
            } else if (j == 2) {                 // intra-lane pairs (e, e+2)
                #pragma unroll
                for (int e = 0; e < 2; ++e) {
                    const int f = e + 2;
                    const bool up = (((tid * 4 + e) & k) == 0);
                    const float a = x[e], b2 = x[f];
                    x[e] = up ? fminf(a, b2) : fmaxf(a, b2);
                    x[f] = up ? fmaxf(a, b2) : fminf(a, b2);
                }
            } else {                             // j == 1: pairs (0,1),(2,3)
                #pragma unroll
                for (int e = 0; e < 4; e += 2) {
                    const int f = e + 1;
                    const bool up = (((tid * 4 + e) & k) == 0);
                    const float a = x[e], b2 = x[f];
                    x[e] = up ? fminf(a, b2) : fmaxf(a, b2);
                    x[f] = up ? fmaxf(a, b2) : fminf(a, b2);
                }
            }
        }
    }

    // Publish sorted vector once.
    ((float4*)s)[tid] = make_float4(x[0], x[1], x[2], x[3]);
    __syncthreads();

    const float vmin = s[0];
    // Descending-rank weight for original index r = 4*tid+e: s[1023-r] - vmin.
    const float4 dsc = ((const float4*)s)[255 - tid];   // s[1020-4t .. 1023-4t]
    const float u[4] = { dsc.w - vmin, dsc.z - vmin, dsc.y - vmin, dsc.x - vmin };

    // Top-16 partial (threads 0..3 read s[1008..1023]).
    float t16p = 0.f;
    if (tid < 4) {
        const float4 q = ((const float4*)s)[252 + tid];
        t16p = q.x + q.y + q.z + q.w;
    }

    float Su = 0.f, U2 = 0.f, A = 0.f, Bx = 0.f, By = 0.f;
    {
        const float ex0 = a01.x - b01.x, ey0 = a01.y - b01.y;
        const float ex1 = a01.z - b01.z, ey1 = a01.w - b01.w;
        const float ex2 = a23.x - b23.x, ey2 = a23.y - b23.y;
        const float ex3 = a23.z - b23.z, ey3 = a23.w - b23.w;
        const float exs[4] = { ex0, ex1, ex2, ex3 };
        const float eys[4] = { ey0, ey1, ey2, ey3 };
        #pragma unroll
        for (int e = 0; e < 4; ++e) {
            const float uu = u[e], ex = exs[e], ey = eys[e];
            Su += uu; U2 += uu * uu;
            A  += uu * (ex * ex + ey * ey);
            Bx += uu * ex; By += uu * ey;
        }
    }

    float vals[6] = { Su, U2, A, Bx, By, t16p };
    #pragma unroll
    for (int m = 0; m < 6; ++m) {
        const float r = waveSum64(vals[m]);
        if (lane == 63) rbuf[wv][m] = r;
    }
    __syncthreads();

    if (tid == 0) {
        float acc[6];
        #pragma unroll
        for (int m = 0; m < 6; ++m)
            acc[m] = rbuf[0][m] + rbuf[1][m] + rbuf[2][m] + rbuf[3][m];
        const float sim_feat = acc[5] * (1.f / 16.f);
        const float denom = (float)N * (float)N * fmaxf(acc[1], EPS);
        const float dis_loc = (2.f * acc[0] * acc[2] - 2.f * (acc[3] * acc[3] + acc[4] * acc[4])) / denom;
        atomicMaxFloat(out, sim_feat - dis_loc);
    }
}

extern "C" void kernel_launch(void* const* d_in, const int* in_sizes, int n_in,
                              void* d_out, int out_size, void* d_ws, size_t ws_size,
                              hipStream_t stream) {
    const float* gfa = (const float*)d_in[0];  // (8,1024,256)
    const float* ca  = (const float*)d_in[1];  // (8,1024,2)
    const float* gfb = (const float*)d_in[2];  // (8,1024,256)
    const float* cb  = (const float*)d_in[3];  // (8,1024,2)
    float* out = (float*)d_out;

    float* v = (float*)d_ws;                   // 64*1024 floats = 256 KB

    dot_kernel<<<N, 256, 0, stream>>>(gfa, gfb, v, out);
    pair_kernel<<<NPAIR, 256, 0, stream>>>(v, ca, cb, out);
}

// Round 8
// 19.987 us; speedup vs baseline: 1.8218x; 1.0362x over previous
//
#include <hip/hip_runtime.h>
#include <math.h>

#define EPS 1e-12f

constexpr int N = 1024;
constexpr int F = 256;
constexpr int NPAIR = 64;

template <int CTRL>
__device__ __forceinline__ float dppAdd(float x) {
    int y = __builtin_amdgcn_update_dpp(0, __float_as_int(x), CTRL, 0xf, 0xf, true);
    return x + __int_as_float(y);
}
// Full wave-64 sum, VALU-only (no DS pipe). Valid in lane 63. (HW-validated R4/R6.)
__device__ __forceinline__ float waveSum64(float x) {
    x = dppAdd<0x111>(x);   // row_shr:1
    x = dppAdd<0x112>(x);   // row_shr:2
    x = dppAdd<0x114>(x);   // row_shr:4
    x = dppAdd<0x118>(x);   // row_shr:8
    x = dppAdd<0x142>(x);   // row_bcast:15
    x = dppAdd<0x143>(x);   // row_bcast:31 -> lane63 = total
    return x;
}

__device__ __forceinline__ float dot4(float4 a, float4 b) {
    return a.x * b.x + a.y * b.y + a.z * b.z + a.w * b.w;
}

__device__ inline void atomicMaxFloat(float* addr, float val) {
    unsigned int* ua = (unsigned int*)addr;
    unsigned int old = __hip_atomic_load(ua, __ATOMIC_RELAXED, __HIP_MEMORY_SCOPE_AGENT);
    while (__uint_as_float(old) < val) {
        unsigned int assumed = old;
        old = atomicCAS(ua, assumed, __float_as_uint(val));
        if (old == assumed) break;
    }
}

// Kernel 1 (R6 DPP version, verbatim — HW-validated bit-exact): 256 blocks x
// 1024 threads; each 256-thread sub-group handles one n. One barrier, zero
// bpermutes: all 26 reductions per wave via DPP. Lane 63 writes 16 dots.
__global__ __launch_bounds__(1024) void dot_kernel(const float* __restrict__ gfa,
                                                   const float* __restrict__ gfb,
                                                   float* __restrict__ v,
                                                   float* __restrict__ out) {
    __shared__ float4 rows[4][16][64];     // [sub][row][lane4], 64 KB
    const unsigned b    = blockIdx.x;      // 0..255
    const unsigned tid  = threadIdx.x;     // 0..1023
    const unsigned sub  = tid >> 8;        // 0..3
    const unsigned t    = tid & 255;       // 0..255
    const unsigned lane = tid & 63;
    const unsigned wv   = t >> 6;          // 0..3
    const unsigned n    = b * 4 + sub;     // 0..1023

    if (b == 0 && tid == 0)
        __hip_atomic_store(out, -INFINITY, __ATOMIC_RELAXED, __HIP_MEMORY_SCOPE_AGENT);

    #pragma unroll
    for (int rep = 0; rep < 4; ++rep) {
        const int idx = rep * 256 + (int)t;   // 0..1023
        const int row = idx >> 6;             // 0..15 (wave-uniform)
        const int c4  = idx & 63;
        const float* src = (row < 8) ? gfa + ((size_t)row * N + n) * F
                                     : gfb + ((size_t)(row - 8) * N + n) * F;
        rows[sub][row][c4] = ((const float4*)src)[c4];
    }
    __syncthreads();

    const int ra0 = 2 * (int)wv, ra1 = ra0 + 1;
    const float4 a0 = rows[sub][ra0][lane];
    const float4 a1 = rows[sub][ra1][lane];
    float4 bb[8];
    #pragma unroll
    for (int rb = 0; rb < 8; ++rb) bb[rb] = rows[sub][8 + rb][lane];

    float na0 = waveSum64(dot4(a0, a0));
    float na1 = waveSum64(dot4(a1, a1));
    float nb[8], d0[8], d1[8];
    #pragma unroll
    for (int rb = 0; rb < 8; ++rb) {
        nb[rb] = waveSum64(dot4(bb[rb], bb[rb]));
        d0[rb] = waveSum64(dot4(a0, bb[rb]));
        d1[rb] = waveSum64(dot4(a1, bb[rb]));
    }
    if (lane == 63) {
        const float ia0 = 1.f / fmaxf(sqrtf(na0), EPS);
        const float ia1 = 1.f / fmaxf(sqrtf(na1), EPS);
        #pragma unroll
        for (int rb = 0; rb < 8; ++rb) {
            const float ib = 1.f / fmaxf(sqrtf(nb[rb]), EPS);
            v[(size_t)(ra0 * 8 + rb) * N + n] = d0[rb] * ia0 * ib;
            v[(size_t)(ra1 * 8 + rb) * N + n] = d1[rb] * ia1 * ib;
        }
    }
}

// Kernel 2 (R7 version, verbatim — passed at 20.7 us): 64 blocks x 256
// threads (4 waves). Register bitonic, 4 elems/lane; 6 barriers total.
__global__ __launch_bounds__(256) void pair_kernel(const float* __restrict__ v,
                                                   const float* __restrict__ ca,
                                                   const float* __restrict__ cb,
                                                   float* __restrict__ out) {
    const int p = blockIdx.x;        // 0..63
    const int ra = p >> 3, rb = p & 7;
    const int tid = threadIdx.x;     // 0..255
    const int lane = tid & 63, wv = tid >> 6;
    __shared__ float s[N];
    __shared__ float rbuf[4][6];

    // Coord loads issued early (original indices r = 4*tid .. 4*tid+3).
    const float4* pa4 = (const float4*)(ca + (size_t)ra * N * 2) + tid * 2;
    const float4* pb4 = (const float4*)(cb + (size_t)rb * N * 2) + tid * 2;
    const float4 a01 = pa4[0], a23 = pa4[1];
    const float4 b01 = pb4[0], b23 = pb4[1];

    const float4 xv = ((const float4*)(v + (size_t)p * N))[tid];
    float x[4] = { xv.x, xv.y, xv.z, xv.w };

    // Bitonic sort ascending over i = tid*4 + e.
    // keepMin = (hiPartner != ascending)
    #pragma unroll
    for (int k = 2; k <= 1024; k <<= 1) {
        #pragma unroll
        for (int j = k >> 1; j >= 1; j >>= 1) {
            if (j >= 256) {                      // cross-wave via LDS
                ((float4*)s)[tid] = make_float4(x[0], x[1], x[2], x[3]);
                __syncthreads();
                const float4 yv = ((const float4*)s)[tid ^ (j >> 2)];
                const float y[4] = { yv.x, yv.y, yv.z, yv.w };
                const bool up = ((tid & (k >> 2)) == 0);
                const bool hi = ((tid & (j >> 2)) != 0);
                const bool keepMin = (hi != up);
                #pragma unroll
                for (int e = 0; e < 4; ++e)
                    x[e] = keepMin ? fminf(x[e], y[e]) : fmaxf(x[e], y[e]);
                __syncthreads();
            } else if (j >= 4) {                 // cross-lane within wave
                const int J = j >> 2;            // 1..32
                const bool up = ((tid & (k >> 2)) == 0);   // k >= 8 here
                const bool hi = ((lane & J) != 0);
                const bool keepMin = (hi != up);
                #pragma unroll
                for (int e = 0; e < 4; ++e) {
                    const float y = __shfl_xor(x[e], J);
                    x[e] = keepMin ? fminf(x[e], y) : fmaxf(x[e], y);
                }
            } else if (j == 2) {                 // intra-lane pairs (e, e+2)
                #pragma unroll
                for (int e = 0; e < 2; ++e) {
                    const int f = e + 2;
                    const bool up = (((tid * 4 + e) & k) == 0);
                    const float a = x[e], b2 = x[f];
                    x[e] = up ? fminf(a, b2) : fmaxf(a, b2);
                    x[f] = up ? fmaxf(a, b2) : fminf(a, b2);
                }
            } else {                             // j == 1: pairs (0,1),(2,3)
                #pragma unroll
                for (int e = 0; e < 4; e += 2) {
                    const int f = e + 1;
                    const bool up = (((tid * 4 + e) & k) == 0);
                    const float a = x[e], b2 = x[f];
                    x[e] = up ? fminf(a, b2) : fmaxf(a, b2);
                    x[f] = up ? fmaxf(a, b2) : fminf(a, b2);
                }
            }
        }
    }

    // Publish sorted vector once.
    ((float4*)s)[tid] = make_float4(x[0], x[1], x[2], x[3]);
    __syncthreads();

    const float vmin = s[0];
    // Descending-rank weight for original index r = 4*tid+e: s[1023-r] - vmin.
    const float4 dsc = ((const float4*)s)[255 - tid];   // s[1020-4t .. 1023-4t]
    const float u[4] = { dsc.w - vmin, dsc.z - vmin, dsc.y - vmin, dsc.x - vmin };

    // Top-16 partial (threads 0..3 read s[1008..1023]).
    float t16p = 0.f;
    if (tid < 4) {
        const float4 q = ((const float4*)s)[252 + tid];
        t16p = q.x + q.y + q.z + q.w;
    }

    float Su = 0.f, U2 = 0.f, A = 0.f, Bx = 0.f, By = 0.f;
    {
        const float exs[4] = { a01.x - b01.x, a01.z - b01.z, a23.x - b23.x, a23.z - b23.z };
        const float eys[4] = { a01.y - b01.y, a01.w - b01.w, a23.y - b23.y, a23.w - b23.w };
        #pragma unroll
        for (int e = 0; e < 4; ++e) {
            const float uu = u[e], ex = exs[e], ey = eys[e];
            Su += uu; U2 += uu * uu;
            A  += uu * (ex * ex + ey * ey);
            Bx += uu * ex; By += uu * ey;
        }
    }

    float vals[6] = { Su, U2, A, Bx, By, t16p };
    #pragma unroll
    for (int m = 0; m < 6; ++m) {
        const float r = waveSum64(vals[m]);
        if (lane == 63) rbuf[wv][m] = r;
    }
    __syncthreads();

    if (tid == 0) {
        float acc[6];
        #pragma unroll
        for (int m = 0; m < 6; ++m)
            acc[m] = rbuf[0][m] + rbuf[1][m] + rbuf[2][m] + rbuf[3][m];
        const float sim_feat = acc[5] * (1.f / 16.f);
        const float denom = (float)N * (float)N * fmaxf(acc[1], EPS);
        const float dis_loc = (2.f * acc[0] * acc[2] - 2.f * (acc[3] * acc[3] + acc[4] * acc[4])) / denom;
        atomicMaxFloat(out, sim_feat - dis_loc);
    }
}

extern "C" void kernel_launch(void* const* d_in, const int* in_sizes, int n_in,
                              void* d_out, int out_size, void* d_ws, size_t ws_size,
                              hipStream_t stream) {
    const float* gfa = (const float*)d_in[0];  // (8,1024,256)
    const float* ca  = (const float*)d_in[1];  // (8,1024,2)
    const float* gfb = (const float*)d_in[2];  // (8,1024,256)
    const float* cb  = (const float*)d_in[3];  // (8,1024,2)
    float* out = (float*)d_out;

    float* v = (float*)d_ws;                   // 64*1024 floats = 256 KB

    dot_kernel<<<256, 1024, 0, stream>>>(gfa, gfb, v, out);
    pair_kernel<<<NPAIR, 256, 0, stream>>>(v, ca, cb, out);
}

// Round 9
// 17.690 us; speedup vs baseline: 2.0584x; 1.1299x over previous
//
#include <hip/hip_runtime.h>
#include <math.h>

#define EPS 1e-12f

constexpr int N = 1024;
constexpr int F = 256;
constexpr int NPAIR = 64;

template <int CTRL>
__device__ __forceinline__ float dppAdd(float x) {
    int y = __builtin_amdgcn_update_dpp(0, __float_as_int(x), CTRL, 0xf, 0xf, true);
    return x + __int_as_float(y);
}
// Full wave-64 sum, VALU-only (no DS pipe). Valid in lane 63. (HW-validated R4/R6/R8.)
__device__ __forceinline__ float waveSum64(float x) {
    x = dppAdd<0x111>(x);   // row_shr:1
    x = dppAdd<0x112>(x);   // row_shr:2
    x = dppAdd<0x114>(x);   // row_shr:4
    x = dppAdd<0x118>(x);   // row_shr:8
    x = dppAdd<0x142>(x);   // row_bcast:15
    x = dppAdd<0x143>(x);   // row_bcast:31 -> lane63 = total
    return x;
}

__device__ __forceinline__ float dot4(float4 a, float4 b) {
    return a.x * b.x + a.y * b.y + a.z * b.z + a.w * b.w;
}

__device__ inline void atomicMaxFloat(float* addr, float val) {
    unsigned int* ua = (unsigned int*)addr;
    unsigned int old = __hip_atomic_load(ua, __ATOMIC_RELAXED, __HIP_MEMORY_SCOPE_AGENT);
    while (__uint_as_float(old) < val) {
        unsigned int assumed = old;
        old = atomicCAS(ua, assumed, __float_as_uint(val));
        if (old == assumed) break;
    }
}

// Kernel 1: ONE WAVE PER n. No LDS, no barriers. Each wave loads all 16 rows
// directly (coalesced float4; b-rows L1-resident across the 4 waves/CU),
// computes 16 norms + 64 dots via DPP (80 waveSum64 — fewer than the 104 of
// the 4-wave LDS version, which recomputed nb per wave). Lane 63 stores.
__global__ __launch_bounds__(64) void dot_kernel(const float* __restrict__ gfa,
                                                 const float* __restrict__ gfb,
                                                 float* __restrict__ v,
                                                 float* __restrict__ out) {
    const int n = blockIdx.x;       // 0..1023
    const int lane = threadIdx.x;   // 0..63

    if (n == 0 && lane == 0)
        __hip_atomic_store(out, -INFINITY, __ATOMIC_RELAXED, __HIP_MEMORY_SCOPE_AGENT);

    const float4* A4 = (const float4*)gfa;   // row r of n starts at (r*N+n)*64
    const float4* B4 = (const float4*)gfb;

    float4 a[8], b[8];
    #pragma unroll
    for (int r = 0; r < 8; ++r) {
        a[r] = A4[((size_t)r * N + n) * 64 + lane];
        b[r] = B4[((size_t)r * N + n) * 64 + lane];
    }

    // Norms (16 sums), then inverse norms computed by all lanes (valid in 63).
    float inva[8], invb[8];
    #pragma unroll
    for (int r = 0; r < 8; ++r) {
        const float na = waveSum64(dot4(a[r], a[r]));
        const float nb = waveSum64(dot4(b[r], b[r]));
        inva[r] = 1.f / fmaxf(sqrtf(na), EPS);
        invb[r] = 1.f / fmaxf(sqrtf(nb), EPS);
    }

    // 64 dots, 8 at a time to bound register liveness.
    #pragma unroll
    for (int ra = 0; ra < 8; ++ra) {
        float d[8];
        #pragma unroll
        for (int rb = 0; rb < 8; ++rb)
            d[rb] = waveSum64(dot4(a[ra], b[rb]));
        if (lane == 63) {
            #pragma unroll
            for (int rb = 0; rb < 8; ++rb)
                v[(size_t)(ra * 8 + rb) * N + n] = d[rb] * inva[ra] * invb[rb];
        }
    }
}

// Kernel 2 (R7 version, verbatim — proven at 20.7/20.0 us): 64 blocks x 256
// threads (4 waves). Register bitonic, 4 elems/lane; 6 barriers total.
__global__ __launch_bounds__(256) void pair_kernel(const float* __restrict__ v,
                                                   const float* __restrict__ ca,
                                                   const float* __restrict__ cb,
                                                   float* __restrict__ out) {
    const int p = blockIdx.x;        // 0..63
    const int ra = p >> 3, rb = p & 7;
    const int tid = threadIdx.x;     // 0..255
    const int lane = tid & 63, wv = tid >> 6;
    __shared__ float s[N];
    __shared__ float rbuf[4][6];

    // Coord loads issued early (original indices r = 4*tid .. 4*tid+3).
    const float4* pa4 = (const float4*)(ca + (size_t)ra * N * 2) + tid * 2;
    const float4* pb4 = (const float4*)(cb + (size_t)rb * N * 2) + tid * 2;
    const float4 a01 = pa4[0], a23 = pa4[1];
    const float4 b01 = pb4[0], b23 = pb4[1];

    const float4 xv = ((const float4*)(v + (size_t)p * N))[tid];
    float x[4] = { xv.x, xv.y, xv.z, xv.w };

    // Bitonic sort ascending over i = tid*4 + e.
    // keepMin = (hiPartner != ascending)
    #pragma unroll
    for (int k = 2; k <= 1024; k <<= 1) {
        #pragma unroll
        for (int j = k >> 1; j >= 1; j >>= 1) {
            if (j >= 256) {                      // cross-wave via LDS
                ((float4*)s)[tid] = make_float4(x[0], x[1], x[2], x[3]);
                __syncthreads();
                const float4 yv = ((const float4*)s)[tid ^ (j >> 2)];
                const float y[4] = { yv.x, yv.y, yv.z, yv.w };
                const bool up = ((tid & (k >> 2)) == 0);
                const bool hi = ((tid & (j >> 2)) != 0);
                const bool keepMin = (hi != up);
                #pragma unroll
                for (int e = 0; e < 4; ++e)
                    x[e] = keepMin ? fminf(x[e], y[e]) : fmaxf(x[e], y[e]);
                __syncthreads();
            } else if (j >= 4) {                 // cross-lane within wave
                const int J = j >> 2;            // 1..32
                const bool up = ((tid & (k >> 2)) == 0);   // k >= 8 here
                const bool hi = ((lane & J) != 0);
                const bool keepMin = (hi != up);
                #pragma unroll
                for (int e = 0; e < 4; ++e) {
                    const float y = __shfl_xor(x[e], J);
                    x[e] = keepMin ? fminf(x[e], y) : fmaxf(x[e], y);
                }
            } else if (j == 2) {                 // intra-lane pairs (e, e+2)
                #pragma unroll
                for (int e = 0; e < 2; ++e) {
                    const int f = e + 2;
                    const bool up = (((tid * 4 + e) & k) == 0);
                    const float a = x[e], b2 = x[f];
                    x[e] = up ? fminf(a, b2) : fmaxf(a, b2);
                    x[f] = up ? fmaxf(a, b2) : fminf(a, b2);
                }
            } else {                             // j == 1: pairs (0,1),(2,3)
                #pragma unroll
                for (int e = 0; e < 4; e += 2) {
                    const int f = e + 1;
                    const bool up = (((tid * 4 + e) & k) == 0);
                    const float a = x[e], b2 = x[f];
                    x[e] = up ? fminf(a, b2) : fmaxf(a, b2);
                    x[f] = up ? fmaxf(a, b2) : fminf(a, b2);
                }
            }
        }
    }

    // Publish sorted vector once.
    ((float4*)s)[tid] = make_float4(x[0], x[1], x[2], x[3]);
    __syncthreads();

    const float vmin = s[0];
    // Descending-rank weight for original index r = 4*tid+e: s[1023-r] - vmin.
    const float4 dsc = ((const float4*)s)[255 - tid];   // s[1020-4t .. 1023-4t]
    const float u[4] = { dsc.w - vmin, dsc.z - vmin, dsc.y - vmin, dsc.x - vmin };

    // Top-16 partial (threads 0..3 read s[1008..1023]).
    float t16p = 0.f;
    if (tid < 4) {
        const float4 q = ((const float4*)s)[252 + tid];
        t16p = q.x + q.y + q.z + q.w;
    }

    float Su = 0.f, U2 = 0.f, A = 0.f, Bx = 0.f, By = 0.f;
    {
        const float exs[4] = { a01.x - b01.x, a01.z - b01.z, a23.x - b23.x, a23.z - b23.z };
        const float eys[4] = { a01.y - b01.y, a01.w - b01.w, a23.y - b23.y, a23.w - b23.w };
        #pragma unroll
        for (int e = 0; e < 4; ++e) {
            const float uu = u[e], ex = exs[e], ey = eys[e];
            Su += uu; U2 += uu * uu;
            A  += uu * (ex * ex + ey * ey);
            Bx += uu * ex; By += uu * ey;
        }
    }

    float vals[6] = { Su, U2, A, Bx, By, t16p };
    #pragma unroll
    for (int m = 0; m < 6; ++m) {
        const float r = waveSum64(vals[m]);
        if (lane == 63) rbuf[wv][m] = r;
    }
    __syncthreads();

    if (tid == 0) {
        float acc[6];
        #pragma unroll
        for (int m = 0; m < 6; ++m)
            acc[m] = rbuf[0][m] + rbuf[1][m] + rbuf[2][m] + rbuf[3][m];
        const float sim_feat = acc[5] * (1.f / 16.f);
        const float denom = (float)N * (float)N * fmaxf(acc[1], EPS);
        const float dis_loc = (2.f * acc[0] * acc[2] - 2.f * (acc[3] * acc[3] + acc[4] * acc[4])) / denom;
        atomicMaxFloat(out, sim_feat - dis_loc);
    }
}

extern "C" void kernel_launch(void* const* d_in, const int* in_sizes, int n_in,
                              void* d_out, int out_size, void* d_ws, size_t ws_size,
                              hipStream_t stream) {
    const float* gfa = (const float*)d_in[0];  // (8,1024,256)
    const float* ca  = (const float*)d_in[1];  // (8,1024,2)
    const float* gfb = (const float*)d_in[2];  // (8,1024,256)
    const float* cb  = (const float*)d_in[3];  // (8,1024,2)
    float* out = (float*)d_out;

    float* v = (float*)d_ws;                   // 64*1024 floats = 256 KB

    dot_kernel<<<N, 64, 0, stream>>>(gfa, gfb, v, out);
    pair_kernel<<<NPAIR, 256, 0, stream>>>(v, ca, cb, out);
}